// Round 4
// baseline (48.608 us; speedup 1.0000x reference)
//
#include <hip/hip_runtime.h>
#include <hip/hip_bf16.h>

// Problem constants (reference: N,E,H,L = 64,64,768,512; eps=1e-12)
#define Nn 64
#define Ee 64
#define Hh 768
#define Ll 512

typedef __attribute__((ext_vector_type(8))) short bf16x8; // 8 bf16 = 4 VGPRs (MFMA A/B frag)
typedef __attribute__((ext_vector_type(4))) float f32x4;  // MFMA C/D frag

#define SROW 40   // shorts per state-LDS row (32 e + 8 pad) -> 80B: 16B-aligned, uniform quad spread
#define MROW 72   // shorts per mapping-LDS row (64 e + 8 pad) -> 144B: 16B-aligned

__device__ __forceinline__ unsigned short f2bf(float x) {
    union { __hip_bfloat16 b; unsigned short u; } cv;
    cv.b = __float2bfloat16(x);
    return cv.u;
}

// ---------------------------------------------------------------------------
// ONE fused kernel: per block (n, 32-l tile):
//   1. stage mapping[n][:, l0..l0+31] -> sM[l][e] bf16 (block-wide, coalesced reads)
//   2. stage state[n][e-half][wave's 192 h] -> sS[w][h'][e] bf16 (wave-local)
//   3. MFMA k-half 0 (acc += A*B), barrier, restage e-half 1, MFMA k-half 1
//   4. LayerNorm over H=768 (shuffle + tiny LDS cross-wave reduce)
//   5. float4 stores
// A = state frag (M-rows = h), B = mapping frag (N-cols = l); D row=(lane>>4)*4+reg
// gives each lane 4 consecutive h -> direct float4 stores. Fragment/LN/epilogue
// math identical to the R2/R3-verified kernel; only the operand source moved
// from a pre-transposed global buffer to in-block LDS staging.
// LDS: 60 KB (sS) + 4.5 KB (sM) + 1 KB (red) = 67 KB -> 2 blocks/CU.
// ---------------------------------------------------------------------------
__global__ __launch_bounds__(256, 2) void fused_expand_ln(
    const float* __restrict__ state,   // [N][E][H]
    const float* __restrict__ mapping, // [N][E][L]
    const float* __restrict__ gamma,
    const float* __restrict__ beta,
    float* __restrict__ out)           // [N][L][H]
{
    __shared__ unsigned short sS[4][192][SROW];
    __shared__ unsigned short sM[32][MROW];
    __shared__ float redS[32][4];
    __shared__ float redQ[32][4];

    const int p    = blockIdx.x;
    const int n    = ((p >> 7) << 3) | (p & 7);   // bijective XCD-friendly map (kept from R3)
    const int l0   = ((p >> 3) & 15) << 5;        // 32 l-rows per block
    const int tid  = threadIdx.x;
    const int w    = tid >> 6;        // wave 0..3 -> h slice [w*192, w*192+192)
    const int lane = tid & 63;
    const int g    = lane >> 4;       // k-group 0..3
    const int c    = lane & 15;       // operand row index (h for A, l for B)

    const float* stn = state   + (size_t)n * (Ee * Hh);
    const float* mpn = mapping + (size_t)n * (Ee * Ll);

    // ---------------- stage mapping (block-wide, once) ----------------
#pragma unroll
    for (int i = 0; i < 2; ++i) {
        int idx = i * 256 + tid;   // 0..511
        int e   = idx >> 3;        // 0..63
        int lq  = idx & 7;         // 0..7 -> l-offset lq*4
        float4 v = *reinterpret_cast<const float4*>(mpn + (size_t)e * Ll + l0 + lq * 4);
        sM[lq * 4 + 0][e] = f2bf(v.x);
        sM[lq * 4 + 1][e] = f2bf(v.y);
        sM[lq * 4 + 2][e] = f2bf(v.z);
        sM[lq * 4 + 3][e] = f2bf(v.w);
    }

    // ---------------- stage state e-half 0 (wave-local region) ----------------
    const int se = lane & 31;          // e within half
    const int hh = (lane >> 5) * 96;   // h sub-slice 0 or 96
    {
        const float* sp = stn + (size_t)se * Hh + w * 192 + hh;
#pragma unroll
        for (int x = 0; x < 24; ++x) {
            float4 v = *reinterpret_cast<const float4*>(sp + x * 4);
            sS[w][hh + x * 4 + 0][se] = f2bf(v.x);
            sS[w][hh + x * 4 + 1][se] = f2bf(v.y);
            sS[w][hh + x * 4 + 2][se] = f2bf(v.z);
            sS[w][hh + x * 4 + 3][se] = f2bf(v.w);
        }
    }
    __syncthreads();

    f32x4 acc[12][2];
#pragma unroll
    for (int t = 0; t < 12; ++t)
#pragma unroll
        for (int u = 0; u < 2; ++u) acc[t][u] = (f32x4){0.f, 0.f, 0.f, 0.f};

    // ---------------- MFMA k-half 0 (e = 0..31) ----------------
    {
        bf16x8 b[2];
#pragma unroll
        for (int u = 0; u < 2; ++u)
            b[u] = *reinterpret_cast<const bf16x8*>(&sM[u * 16 + c][g * 8]);
#pragma unroll
        for (int t = 0; t < 12; ++t) {
            bf16x8 a = *reinterpret_cast<const bf16x8*>(&sS[w][t * 16 + c][g * 8]);
#pragma unroll
            for (int u = 0; u < 2; ++u)
                acc[t][u] = __builtin_amdgcn_mfma_f32_16x16x32_bf16(a, b[u], acc[t][u], 0, 0, 0);
        }
    }
    __syncthreads();   // WAR: all half-0 frag reads complete before region rewrite

    // ---------------- stage state e-half 1 (e = 32..63) ----------------
    {
        const float* sp = stn + (size_t)(32 + se) * Hh + w * 192 + hh;
#pragma unroll
        for (int x = 0; x < 24; ++x) {
            float4 v = *reinterpret_cast<const float4*>(sp + x * 4);
            sS[w][hh + x * 4 + 0][se] = f2bf(v.x);
            sS[w][hh + x * 4 + 1][se] = f2bf(v.y);
            sS[w][hh + x * 4 + 2][se] = f2bf(v.z);
            sS[w][hh + x * 4 + 3][se] = f2bf(v.w);
        }
    }
    __syncthreads();

    // ---------------- MFMA k-half 1 ----------------
    {
        bf16x8 b[2];
#pragma unroll
        for (int u = 0; u < 2; ++u)
            b[u] = *reinterpret_cast<const bf16x8*>(&sM[u * 16 + c][32 + g * 8]);
#pragma unroll
        for (int t = 0; t < 12; ++t) {
            bf16x8 a = *reinterpret_cast<const bf16x8*>(&sS[w][t * 16 + c][g * 8]);
#pragma unroll
            for (int u = 0; u < 2; ++u)
                acc[t][u] = __builtin_amdgcn_mfma_f32_16x16x32_bf16(a, b[u], acc[t][u], 0, 0, 0);
        }
    }

    // ---------------- LayerNorm over H=768 ----------------
    // Lane holds l rows (l0+u*16+c) and h values {w*192 + t*16 + g*4 + r}.
    float s[2] = {0.f, 0.f}, q[2] = {0.f, 0.f};
#pragma unroll
    for (int t = 0; t < 12; ++t)
#pragma unroll
        for (int u = 0; u < 2; ++u)
#pragma unroll
            for (int r = 0; r < 4; ++r) {
                float v = acc[t][u][r];
                s[u] += v;
                q[u] += v * v;
            }
    // Sum over g (lanes c, c+16, c+32, c+48): two butterfly steps.
#pragma unroll
    for (int off = 16; off < 64; off <<= 1)
#pragma unroll
        for (int u = 0; u < 2; ++u) {
            s[u] += __shfl_xor(s[u], off, 64);
            q[u] += __shfl_xor(q[u], off, 64);
        }
    // Cross-wave combine: each wave has the partial over its 192-h slice.
    if (g == 0) {
#pragma unroll
        for (int u = 0; u < 2; ++u) {
            redS[u * 16 + c][w] = s[u];
            redQ[u * 16 + c][w] = q[u];
        }
    }
    __syncthreads();

    float mu[2], rstd[2];
#pragma unroll
    for (int u = 0; u < 2; ++u) {
        int li = u * 16 + c;
        float S = redS[li][0] + redS[li][1] + redS[li][2] + redS[li][3];
        float Q = redQ[li][0] + redQ[li][1] + redQ[li][2] + redQ[li][3];
        float m = S * (1.f / Hh);
        float v = Q * (1.f / Hh) - m * m;
        mu[u]   = m;
        rstd[u] = rsqrtf(v + 1e-12f);
    }

    // ---------------- Epilogue: normalize + gamma/beta + float4 stores ----------------
#pragma unroll
    for (int t = 0; t < 12; ++t) {
        int hb = w * 192 + t * 16 + g * 4;
        f32x4 gm = *reinterpret_cast<const f32x4*>(gamma + hb);
        f32x4 bt = *reinterpret_cast<const f32x4*>(beta + hb);
#pragma unroll
        for (int u = 0; u < 2; ++u) {
            f32x4 v;
#pragma unroll
            for (int r = 0; r < 4; ++r)
                v[r] = (acc[t][u][r] - mu[u]) * rstd[u] * gm[r] + bt[r];
            *reinterpret_cast<f32x4*>(
                out + (size_t)(n * Ll + l0 + u * 16 + c) * Hh + hb) = v;
        }
    }
}

extern "C" void kernel_launch(void* const* d_in, const int* in_sizes, int n_in,
                              void* d_out, int out_size, void* d_ws, size_t ws_size,
                              hipStream_t stream)
{
    const float* state   = (const float*)d_in[0]; // (N,E,H)
    const float* mapping = (const float*)d_in[1]; // (N,E,L)
    const float* gamma   = (const float*)d_in[2]; // (H,)
    const float* beta    = (const float*)d_in[3]; // (H,)
    float* out           = (float*)d_out;         // (N,L,H)

    fused_expand_ln<<<Nn * (Ll / 32), 256, 0, stream>>>(state, mapping, gamma, beta, out);
}

// Round 5
// 45.987 us; speedup vs baseline: 1.0570x; 1.0570x over previous
//
#include <hip/hip_runtime.h>
#include <hip/hip_bf16.h>

// Problem constants (reference: N,E,H,L = 64,64,768,512; eps=1e-12)
#define Nn 64
#define Ee 64
#define Hh 768
#define Ll 512
#define NEH (Nn * Ee * Hh) // 3145728 state elems
#define NEL (Nn * Ee * Ll) // 2097152 mapping elems

typedef __attribute__((ext_vector_type(8))) short bf16x8; // 8 bf16 = 4 VGPRs (MFMA A/B frag)
typedef __attribute__((ext_vector_type(4))) float f32x4;  // MFMA C/D frag

// ---------------------------------------------------------------------------
// Pre-pass: fp32 -> bf16 convert + transpose, LDS-tiled, both sides coalesced
// (full 128B-line writes: 16 lanes x 8B cover one 128B row, 4 rows/instr).
//   sT[n][h][e]  (H x E per n)   mT[n][l][e]  (L x E per n)
// ---------------------------------------------------------------------------
__global__ __launch_bounds__(256) void cvt_transpose(
    const float* __restrict__ state, const float* __restrict__ mapping,
    __hip_bfloat16* __restrict__ sT, __hip_bfloat16* __restrict__ mT)
{
    __shared__ unsigned short lds[64][66]; // [x][e]

    int b = blockIdx.x;
    const float* src;
    __hip_bfloat16* dst;
    int W, x0;
    if (b < Nn * (Hh / 64)) {            // state tiles
        int n = b / (Hh / 64);
        x0 = (b % (Hh / 64)) * 64;
        src = state + (size_t)n * Ee * Hh;
        dst = sT + (size_t)n * Hh * Ee;
        W = Hh;
    } else {                              // mapping tiles
        b -= Nn * (Hh / 64);
        int n = b / (Ll / 64);
        x0 = (b % (Ll / 64)) * 64;
        src = mapping + (size_t)n * Ee * Ll;
        dst = mT + (size_t)n * Ll * Ee;
        W = Ll;
    }

    // Read phase: each thread loads float2 (2 x's) of one e-row.
    const int xr = (threadIdx.x & 31) * 2;
    const int er = threadIdx.x >> 5;  // 0..7
#pragma unroll
    for (int i = 0; i < 8; ++i) {
        int e = i * 8 + er;
        float2 v = *reinterpret_cast<const float2*>(src + (size_t)e * W + x0 + xr);
        union { __hip_bfloat16 b16; unsigned short u; } c0, c1;
        c0.b16 = __float2bfloat16(v.x);
        c1.b16 = __float2bfloat16(v.y);
        lds[xr][e]     = c0.u;
        lds[xr + 1][e] = c1.u;
    }
    __syncthreads();

    // Write phase: each thread packs 4 bf16 (contiguous e) -> one 8B store.
    const int e4 = (threadIdx.x & 15) * 4;
    const int xw = threadIdx.x >> 4;   // 0..15
    unsigned short* dsts = reinterpret_cast<unsigned short*>(dst);
#pragma unroll
    for (int i = 0; i < 4; ++i) {
        int x = i * 16 + xw;
        uint2 v;
        v.x = *reinterpret_cast<const unsigned int*>(&lds[x][e4]);
        v.y = *reinterpret_cast<const unsigned int*>(&lds[x][e4 + 2]);
        *reinterpret_cast<uint2*>(dsts + (size_t)(x0 + x) * Ee + e4) = v;
    }
}

// ---------------------------------------------------------------------------
// Fused GEMM (out[n,l,h] = sum_e mapping[n,e,l]*state[n,e,h]) + LayerNorm(H).
// A = state frag (M-rows = h), B = mapping frag (N-cols = l).
//
// R5 change: epilogue bounces the normalized tile through LDS so the global
// stores are LANE-CONTIGUOUS (64 lanes x 16B = 1KB of consecutive, 128B-
// aligned bytes per wave-instr). The old direct store pattern emitted 16x64B
// half-line segments per instr (c spans 16 l-rows 3KB apart) -> 2x write
// transactions per byte -> ~3 TB/s effective; full lines should restore
// fill-kernel-class write BW (6.7-7 TB/s).
// LDS bounce buffer: [16 rows][192 f32x4] = 48KB, 16B-unit XOR swizzle
// (^(row&7)) to break the 16-way write bank conflict. Two 16-row phases.
// ---------------------------------------------------------------------------
__global__ __launch_bounds__(256) void gemm_ln(
    const __hip_bfloat16* __restrict__ sT, // [N][H][E]
    const __hip_bfloat16* __restrict__ mT, // [N][L][E]
    const float* __restrict__ gamma,
    const float* __restrict__ beta,
    float* __restrict__ out)               // [N][L][H]
{
    __shared__ f32x4 bounce[3072];         // 48 KB
    __shared__ float redS[32][4];
    __shared__ float redQ[32][4];

    const int p    = blockIdx.x;
    const int n    = ((p >> 7) << 3) | (p & 7);
    const int l0   = ((p >> 3) & 15) << 5; // 32 rows per tile
    const int tid  = threadIdx.x;
    const int w    = tid >> 6;        // wave 0..3
    const int lane = tid & 63;
    const int g    = lane >> 4;       // k-group 0..3 (also h sub-offset in D)
    const int c    = lane & 15;       // operand row index (h for A, l for B)

    // B fragments (mapping rows l0+u*16+c), k = 8*g + j and +32
    bf16x8 b0[2], b1[2];
#pragma unroll
    for (int u = 0; u < 2; ++u) {
        const __hip_bfloat16* Brow = mT + (size_t)(n * Ll + l0 + u * 16 + c) * Ee + g * 8;
        b0[u] = *reinterpret_cast<const bf16x8*>(Brow);
        b1[u] = *reinterpret_cast<const bf16x8*>(Brow + 32);
    }

    f32x4 acc[12][2];
#pragma unroll
    for (int t = 0; t < 12; ++t)
#pragma unroll
        for (int u = 0; u < 2; ++u) acc[t][u] = (f32x4){0.f, 0.f, 0.f, 0.f};

    const __hip_bfloat16* Abase = sT + (size_t)(n * Hh + w * 192 + c) * Ee + g * 8;
#pragma unroll
    for (int t = 0; t < 12; ++t) {
        const __hip_bfloat16* ap = Abase + (size_t)t * 16 * Ee;
        bf16x8 a0 = *reinterpret_cast<const bf16x8*>(ap);
        bf16x8 a1 = *reinterpret_cast<const bf16x8*>(ap + 32);
#pragma unroll
        for (int u = 0; u < 2; ++u) {
            acc[t][u] = __builtin_amdgcn_mfma_f32_16x16x32_bf16(a0, b0[u], acc[t][u], 0, 0, 0);
            acc[t][u] = __builtin_amdgcn_mfma_f32_16x16x32_bf16(a1, b1[u], acc[t][u], 0, 0, 0);
        }
    }

    // ---------------- LayerNorm over H=768 ----------------
    // Lane holds l rows (l0+u*16+c) and h values {w*192 + t*16 + g*4 + r}.
    float s[2] = {0.f, 0.f}, q[2] = {0.f, 0.f};
#pragma unroll
    for (int t = 0; t < 12; ++t)
#pragma unroll
        for (int u = 0; u < 2; ++u)
#pragma unroll
            for (int r = 0; r < 4; ++r) {
                float v = acc[t][u][r];
                s[u] += v;
                q[u] += v * v;
            }
    // Sum over g (lanes c, c+16, c+32, c+48): two butterfly steps.
#pragma unroll
    for (int off = 16; off < 64; off <<= 1)
#pragma unroll
        for (int u = 0; u < 2; ++u) {
            s[u] += __shfl_xor(s[u], off, 64);
            q[u] += __shfl_xor(q[u], off, 64);
        }
    // Cross-wave combine: each wave has the partial over its 192-h slice.
    if (g == 0) {
#pragma unroll
        for (int u = 0; u < 2; ++u) {
            redS[u * 16 + c][w] = s[u];
            redQ[u * 16 + c][w] = q[u];
        }
    }
    __syncthreads();

    float mu[2], rstd[2];
#pragma unroll
    for (int u = 0; u < 2; ++u) {
        int li = u * 16 + c;
        float S = redS[li][0] + redS[li][1] + redS[li][2] + redS[li][3];
        float Q = redQ[li][0] + redQ[li][1] + redQ[li][2] + redQ[li][3];
        float m = S * (1.f / Hh);
        float v = Q * (1.f / Hh) - m * m;
        mu[u]   = m;
        rstd[u] = rsqrtf(v + 1e-12f);
    }

    // ---------------- Epilogue: normalize -> LDS bounce -> full-line stores ----------------
#pragma unroll
    for (int ph = 0; ph < 2; ++ph) {   // phase ph handles l rows l0+ph*16 .. +15
        // Write: this lane's 12 frags for u==ph into bounce[row=c][c4=w*48+t*4+g],
        // 16B-unit index XOR-swizzled with (row&7) to spread the 16 c-lanes.
#pragma unroll
        for (int t = 0; t < 12; ++t) {
            int hb = w * 192 + t * 16 + g * 4;
            f32x4 gm = *reinterpret_cast<const f32x4*>(gamma + hb);
            f32x4 bt = *reinterpret_cast<const f32x4*>(beta + hb);
            f32x4 v;
#pragma unroll
            for (int r = 0; r < 4; ++r)
                v[r] = (acc[t][ph][r] - mu[ph]) * rstd[ph] * gm[r] + bt[r];
            int unit = c * 192 + w * 48 + t * 4 + g;
            bounce[unit ^ (c & 7)] = v;
        }
        __syncthreads();

        // Read + store: 3072 f32x4 streamed out; thread tid handles f = j*256+tid.
        // Wave-instr = 64 consecutive f32x4 = 1KB contiguous, 128B-aligned.
        float* chunk = out + (size_t)(n * Ll + l0 + ph * 16) * Hh;
#pragma unroll
        for (int j = 0; j < 12; ++j) {
            int f   = j * 256 + tid;
            int row = f / 192;          // l-row within phase
            f32x4 v = bounce[f ^ (row & 7)];
            *reinterpret_cast<f32x4*>(chunk + (size_t)f * 4) = v;
        }
        __syncthreads();   // WAR before next phase overwrites bounce
    }
}

extern "C" void kernel_launch(void* const* d_in, const int* in_sizes, int n_in,
                              void* d_out, int out_size, void* d_ws, size_t ws_size,
                              hipStream_t stream)
{
    const float* state   = (const float*)d_in[0]; // (N,E,H)
    const float* mapping = (const float*)d_in[1]; // (N,E,L)
    const float* gamma   = (const float*)d_in[2]; // (H,)
    const float* beta    = (const float*)d_in[3]; // (H,)
    float* out           = (float*)d_out;         // (N,L,H)

    __hip_bfloat16* sT = (__hip_bfloat16*)d_ws;   // N*H*E bf16
    __hip_bfloat16* mT = sT + NEH;                // N*L*E bf16  (total ws use: 10.5 MB)

    const int tiles = Nn * (Hh / 64) + Nn * (Ll / 64); // 768 + 512 = 1280
    cvt_transpose<<<tiles, 256, 0, stream>>>(state, mapping, sT, mT);
    gemm_ln<<<Nn * (Ll / 32), 256, 0, stream>>>(sT, mT, gamma, beta, out);
}